// Round 5
// baseline (135.297 us; speedup 1.0000x reference)
//
#include <hip/hip_runtime.h>
#include <stdint.h>
#include <math.h>

#define B_ 16
#define NN 16384
#define C_ 90
#define KSEL 100
#define MAXD 100
#define MFLAT (C_ * KSEL)   // 9000
#define NPAIR 128
#define ZKEY 0x80000000u    // fkey(0.0f)

// ---------- helpers ----------

// monotonic float->uint32 key (order-preserving for all non-NaN floats)
__device__ __forceinline__ uint32_t fkey(float f) {
  uint32_t u = __float_as_uint(f);
  return (u & 0x80000000u) ? ~u : (u | 0x80000000u);
}
__device__ __forceinline__ float keyinv(uint32_t k) {
  uint32_t u = (k & 0x80000000u) ? (k & 0x7FFFFFFFu) : ~k;
  return __uint_as_float(u);
}

// block sum over 512 threads (8 waves)
__device__ __forceinline__ uint32_t blockSum512(uint32_t v, uint32_t* red, uint32_t* s_total) {
  int tid = threadIdx.x;
#pragma unroll
  for (int o = 32; o > 0; o >>= 1) v += __shfl_down(v, o, 64);
  if ((tid & 63) == 0) red[tid >> 6] = v;
  __syncthreads();
  if (tid == 0) {
    uint32_t s = 0;
#pragma unroll
    for (int i = 0; i < 8; ++i) s += red[i];
    *s_total = s;
  }
  __syncthreads();
  return *s_total;
}

// block sum over 256 threads (final_topk nz-count + tie fallback)
__device__ __forceinline__ uint32_t blockSum256(uint32_t v, uint32_t* red, uint32_t* s_total) {
  int tid = threadIdx.x;
#pragma unroll
  for (int o = 32; o > 0; o >>= 1) v += __shfl_down(v, o, 64);
  if ((tid & 63) == 0) red[tid >> 6] = v;
  __syncthreads();
  if (tid == 0) *s_total = red[0] + red[1] + red[2] + red[3];
  __syncthreads();
  return *s_total;
}

// ---------- kernel B: transpose [B,N,C] -> [B,C,N] uint16 keys of RAW logits ----------
// k16 = fkey(logit) >> 16 is order-preserving; sigmoid applied later only to winners.
__global__ __launch_bounds__(256) void transpose_key16_kernel(const float* __restrict__ logits,
                                                              uint16_t* __restrict__ keys16T) {
  __shared__ uint32_t tile[128 * 91];   // 128 n-rows x 90 classes (full fkey32), padded
  int b = blockIdx.y;
  int n0 = blockIdx.x * 128;
  const float4* src4 = reinterpret_cast<const float4*>(logits + ((size_t)b * NN + n0) * C_);
  for (int p = threadIdx.x; p < 2880; p += 256) {   // 128*90/4
    float4 v = src4[p];
    int e = p * 4;
    float vv[4] = {v.x, v.y, v.z, v.w};
#pragma unroll
    for (int j = 0; j < 4; ++j) {
      int ee = e + j;
      tile[(ee / C_) * 91 + (ee % C_)] = fkey(vv[j]);
    }
  }
  __syncthreads();
  uint16_t* dstb = keys16T + (size_t)b * C_ * NN + n0;
  for (int q = threadIdx.x; q < C_ * 16; q += 256) {   // 90 classes x 16 uint4 (8 u16 each)
    int c = q >> 4, g = q & 15;
    int nn2 = g * 8;
    uint4 o;
    o.x = (tile[(nn2 + 0) * 91 + c] >> 16) | (tile[(nn2 + 1) * 91 + c] & 0xFFFF0000u);
    o.y = (tile[(nn2 + 2) * 91 + c] >> 16) | (tile[(nn2 + 3) * 91 + c] & 0xFFFF0000u);
    o.z = (tile[(nn2 + 4) * 91 + c] >> 16) | (tile[(nn2 + 5) * 91 + c] & 0xFFFF0000u);
    o.w = (tile[(nn2 + 6) * 91 + c] >> 16) | (tile[(nn2 + 7) * 91 + c] & 0xFFFF0000u);
    reinterpret_cast<uint4*>(dstb + (size_t)c * NN)[g] = o;
  }
}

// ---------- kernel C1: per-(b,c) radix-select top-100 on 16-bit keys ----------
// 512 threads x 32 u16 keys/thread (16 u32 regs). Level 0: 2048 bins (bits 15:5),
// level 1: 32 bins (bits 4:0, redundant all-thread scan). Writes packed (k16<<16|idx).
template <int TR>
__global__ __launch_bounds__(512, 4) void select_kernel(
    const uint16_t* __restrict__ keys16T,  // [B][C][N] (TR=1)
    const float* __restrict__ logits,      // [B][N][C] raw (TR=0 fallback)
    uint32_t* __restrict__ candPacked,     // [B*C][NPAIR]  (k16<<16)|idx
    uint32_t* __restrict__ candCount) {    // [B*C]
  __shared__ uint32_t hist[2048];
  __shared__ uint32_t sc[512];
  __shared__ uint32_t ws8[64];
  __shared__ int s_bsel;
  __shared__ uint32_t s_Sincl, s_Sexcl;
  __shared__ uint32_t red[8];
  __shared__ uint32_t s_total;
  __shared__ uint32_t s_cnt;

  const int c = blockIdx.x, b = blockIdx.y;
  const int tid = threadIdx.x;

  // ---- load 32 u16 keys/thread (16 packed words) ----
  uint32_t keyw[16];
  if (TR) {
    const uint4* src4 = reinterpret_cast<const uint4*>(keys16T + ((size_t)b * C_ + c) * NN);
#pragma unroll
    for (int q = 0; q < 4; ++q) {
      uint4 kv = src4[q * 512 + tid];
      keyw[4 * q + 0] = kv.x; keyw[4 * q + 1] = kv.y;
      keyw[4 * q + 2] = kv.z; keyw[4 * q + 3] = kv.w;
    }
  } else {
    const float* src = logits + (size_t)b * NN * C_ + c;
#pragma unroll
    for (int m = 0; m < 16; ++m) {
      uint32_t i0 = (uint32_t)((((m >> 2) * 512 + tid) * 8) + ((m & 3) * 2));
      uint32_t klo = fkey(src[(size_t)i0 * C_]) >> 16;
      uint32_t khi = fkey(src[(size_t)(i0 + 1) * C_]) >> 16;
      keyw[m] = klo | (khi << 16);
    }
  }

  // ---- level 0: 2048-bin histogram over bits 15:5 ----
  reinterpret_cast<uint4*>(hist)[tid] = make_uint4(0u, 0u, 0u, 0u);   // 2048 words
  __syncthreads();
#pragma unroll
  for (int m = 0; m < 16; ++m) {
    uint32_t w = keyw[m];
    atomicAdd(&hist[(w & 0xFFFFu) >> 5], 1u);
    atomicAdd(&hist[w >> 21], 1u);   // (w>>16)>>5
  }
  __syncthreads();

  uint32_t m_above = 0;
  uint32_t need = 100u;
  uint32_t cut16 = 0;
  int found = 0;
  int tiepath = 0;
  uint32_t V16 = 0, Texact = NN - 1;

  {
    uint32_t h0 = hist[4 * tid], h1 = hist[4 * tid + 1];
    uint32_t h2 = hist[4 * tid + 2], h3 = hist[4 * tid + 3];
    sc[tid] = h0 + h1 + h2 + h3;
    if (tid == 0) s_bsel = -1;
    __syncthreads();
    if (tid < 64) {   // wave 0: inclusive suffix over 8-chunk groups
      uint32_t w = 0;
      int base = tid * 8;
#pragma unroll
      for (int i = 0; i < 8; ++i) w += sc[base + i];
#pragma unroll
      for (int off = 1; off < 64; off <<= 1) {
        uint32_t v = __shfl_down(w, off, 64);
        if (tid + off < 64) w += v;
      }
      ws8[tid] = w;
    }
    __syncthreads();
    {
      int g = tid >> 3;
      uint32_t above = (g < 63) ? ws8[g + 1] : 0u;
      for (int j = (g << 3) + 7; j > tid; --j) above += sc[j];
      uint32_t run = above;
      int best = -1;
      uint32_t bi = 0, be = 0;
      uint32_t hh[4] = {h0, h1, h2, h3};
#pragma unroll
      for (int p = 3; p >= 0; --p) {
        uint32_t h = hh[p];
        run += h;
        if (best < 0 && run >= need) { best = 4 * tid + p; bi = run; be = run - h; }
      }
      if (best >= 0) atomicMax(&s_bsel, best);
      __syncthreads();
      if (best >= 0 && best == s_bsel) { s_Sincl = bi; s_Sexcl = be; }
    }
    __syncthreads();

    uint32_t bsel = (uint32_t)s_bsel;
    uint32_t Sincl = s_Sincl, Sexcl = s_Sexcl;
    if (Sincl <= (uint32_t)NPAIR) {
      cut16 = bsel << 5;
      found = 1;
    } else {
      m_above = Sexcl;
      need = 100u - m_above;
      // ---- level 1: 32 bins (bits 4:0) within prefix bsel ----
      __syncthreads();
      if (tid < 8) reinterpret_cast<uint4*>(hist)[tid] = make_uint4(0u, 0u, 0u, 0u);
      __syncthreads();
#pragma unroll
      for (int m = 0; m < 16; ++m) {
        uint32_t w = keyw[m];
        uint32_t klo = w & 0xFFFFu, khi = w >> 16;
        if ((klo >> 5) == bsel) atomicAdd(&hist[klo & 31u], 1u);
        if ((khi >> 5) == bsel) atomicAdd(&hist[khi & 31u], 1u);
      }
      __syncthreads();
      // redundant all-thread suffix scan over 32 bins (uniform result)
      uint32_t run = 0;
      int b1 = -1;
      uint32_t Si = 0, Se = 0;
      for (int p = 31; p >= 0; --p) {
        uint32_t h = hist[p];
        run += h;
        if (b1 < 0 && run >= need) { b1 = p; Si = run; Se = run - h; }
      }
      uint32_t cutv = (bsel << 5) | (uint32_t)b1;
      if (m_above + Si <= (uint32_t)NPAIR) {
        cut16 = cutv;
        found = 1;
      } else {
        // >128 exact 16-bit ties at the cut (essentially impossible on real data):
        // fall back to index-trimmed tie handling.
        tiepath = 1;
        V16 = cutv;
        m_above += Se;
        uint32_t r = 100u - m_above;
        uint32_t lo2 = 0, hi2 = NN - 1;
        while (lo2 < hi2) {
          uint32_t mid2 = lo2 + ((hi2 - lo2) >> 1);
          uint32_t cnt = 0;
#pragma unroll
          for (int m = 0; m < 16; ++m) {
            uint32_t w = keyw[m];
            uint32_t i0 = (uint32_t)((((m >> 2) * 512 + tid) * 8) + ((m & 3) * 2));
            cnt += ((w & 0xFFFFu) == V16 && i0 <= mid2) ? 1u : 0u;
            cnt += ((w >> 16) == V16 && (i0 + 1) <= mid2) ? 1u : 0u;
          }
          uint32_t tot = blockSum512(cnt, red, &s_total);
          if (tot >= r) hi2 = mid2; else lo2 = mid2 + 1;
        }
        Texact = lo2;
      }
    }
  }

  // ---- collect candidates (100..128) to GLOBAL, unsorted, packed u32 ----
  if (tid == 0) s_cnt = 0;
  __syncthreads();
  uint32_t* outp = candPacked + (size_t)(b * C_ + c) * NPAIR;
#pragma unroll
  for (int m = 0; m < 16; ++m) {
    uint32_t w = keyw[m];
    uint32_t i0 = (uint32_t)((((m >> 2) * 512 + tid) * 8) + ((m & 3) * 2));
    uint32_t klo = w & 0xFFFFu, khi = w >> 16;
    bool t0 = tiepath ? (klo > V16 || (klo == V16 && i0 <= Texact)) : (klo >= cut16);
    bool t1 = tiepath ? (khi > V16 || (khi == V16 && (i0 + 1) <= Texact)) : (khi >= cut16);
    if (t0) {
      uint32_t p = atomicAdd(&s_cnt, 1u);
      if (p < (uint32_t)NPAIR) outp[p] = (klo << 16) | i0;
    }
    if (t1) {
      uint32_t p = atomicAdd(&s_cnt, 1u);
      if (p < (uint32_t)NPAIR) outp[p] = (khi << 16) | (i0 + 1);
    }
  }
  __syncthreads();
  if (tid == 0) candCount[b * C_ + c] = (s_cnt > (uint32_t)NPAIR) ? (uint32_t)NPAIR : s_cnt;
}

// ---------- kernel C2: per-(b,c) exact re-score + sort + decode + bitmask NMS ----------
__global__ __launch_bounds__(128, 4) void sort_nms_kernel(
    const uint32_t* __restrict__ candPacked,  // [B*C][NPAIR]
    const uint32_t* __restrict__ candCount,   // [B*C]
    const float* __restrict__ logits,         // [B][N][C]
    const float* __restrict__ enc,            // [B][N][4]
    const float* __restrict__ anchors,        // [N][4]
    float* __restrict__ candBox,              // [B][C][K][4]
    float* __restrict__ candScore) {          // [B][C][K]
  __shared__ unsigned long long ck[NPAIR];
  __shared__ float s_vals[KSEL];
  __shared__ float s_boxv[KSEL][5];   // padded to 5 to spread LDS banks
  __shared__ float s_area[KSEL];
  __shared__ uint32_t smask[KSEL][4]; // row i: bitmask of victims j (j>i, iou>=thr)
  __shared__ unsigned long long s_keepw[2];

  const int c = blockIdx.x, b = blockIdx.y;
  const int tid = threadIdx.x;
  const int bc = b * C_ + c;

  uint32_t cnt = candCount[bc];
  unsigned long long ckv = 0ull;
  if (tid < (int)cnt) {
    uint32_t v = candPacked[(size_t)bc * NPAIR + tid];
    int n = (int)(v & 0x3FFFu);
    float x = logits[((size_t)b * NN + n) * C_ + c];
    float s = 1.0f / (1.0f + expf(-x));
    ckv = ((unsigned long long)fkey(s) << 32) | (unsigned long long)(~(uint32_t)n);
  }
  ck[tid] = ckv;
  __syncthreads();

  // bitonic sort 128 descending by (exact sigmoid key, ~idx)
  for (int kk = 2; kk <= 128; kk <<= 1) {
    for (int j = kk >> 1; j > 0; j >>= 1) {
      int ixj = tid ^ j;
      if (ixj > tid) {
        unsigned long long a = ck[tid], bb2 = ck[ixj];
        if ((a < bb2) == ((tid & kk) == 0)) { ck[tid] = bb2; ck[ixj] = a; }
      }
      __syncthreads();
    }
  }

  // decode rank tid -> (score, box, area)   (cnt >= 100 always)
  if (tid < KSEL) {
    unsigned long long keyv = ck[tid];
    uint32_t hk = (uint32_t)(keyv >> 32);
    int n = (int)(~(uint32_t)(keyv & 0xFFFFFFFFull)) & (NN - 1);
    s_vals[tid] = keyinv(hk);
    float4 e = reinterpret_cast<const float4*>(enc)[(size_t)b * NN + n];
    float4 a = reinterpret_cast<const float4*>(anchors)[n];
    float ha = a.z - a.x, wa = a.w - a.y;
    float cya = (a.x + a.z) * 0.5f, cxa = (a.y + a.w) * 0.5f;
    float cy = (e.x / 10.0f) * ha + cya;
    float cx = (e.y / 10.0f) * wa + cxa;
    float h = expf(e.z / 5.0f) * ha;
    float w = expf(e.w / 5.0f) * wa;
    float y1 = fminf(fmaxf(cy - h * 0.5f, 0.0f), 1.0f);
    float x1 = fminf(fmaxf(cx - w * 0.5f, 0.0f), 1.0f);
    float y2 = fminf(fmaxf(cy + h * 0.5f, 0.0f), 1.0f);
    float x2 = fminf(fmaxf(cx + w * 0.5f, 0.0f), 1.0f);
    s_boxv[tid][0] = y1; s_boxv[tid][1] = x1; s_boxv[tid][2] = y2; s_boxv[tid][3] = x2;
    s_area[tid] = fmaxf(y2 - y1, 0.0f) * fmaxf(x2 - x1, 0.0f);
    smask[tid][0] = 0; smask[tid][1] = 0; smask[tid][2] = 0; smask[tid][3] = 0;
  }
  __syncthreads();

  // parallel IoU matrix over triangular pairs i<j (suppressor i -> victim j)
  for (int p = tid; p < (KSEL * (KSEL - 1)) / 2; p += 128) {
    int j = (int)((1.0f + sqrtf(1.0f + 8.0f * (float)p)) * 0.5f);
    while (j * (j - 1) / 2 > p) --j;
    while ((j + 1) * j / 2 <= p) ++j;
    int i = p - j * (j - 1) / 2;
    float iy1 = s_boxv[i][0], ix1 = s_boxv[i][1], iy2 = s_boxv[i][2], ix2 = s_boxv[i][3];
    float jy1 = s_boxv[j][0], jx1 = s_boxv[j][1], jy2 = s_boxv[j][2], jx2 = s_boxv[j][3];
    float ta = fmaxf(fminf(iy2, jy2) - fmaxf(iy1, jy1), 0.0f) *
               fmaxf(fminf(ix2, jx2) - fmaxf(ix1, jx1), 0.0f);
    float un = fmaxf(s_area[i] + s_area[j] - ta, 1e-8f);
    if (ta / un >= 0.5f) atomicOr(&smask[i][j >> 5], 1u << (j & 31));
  }
  __syncthreads();

  // serial greedy scan, registers + shfl only, on wave 0
  if (tid < 64) {
    int L = tid;
    unsigned long long r0 = (unsigned long long)smask[L][0] |
                            ((unsigned long long)smask[L][1] << 32);
    unsigned long long r1 = (unsigned long long)smask[L][2] |
                            ((unsigned long long)smask[L][3] << 32);
    unsigned long long r2 = 0, r3 = 0;
    if (L < KSEL - 64) {
      r2 = (unsigned long long)smask[L + 64][0] | ((unsigned long long)smask[L + 64][1] << 32);
      r3 = (unsigned long long)smask[L + 64][2] | ((unsigned long long)smask[L + 64][3] << 32);
    }
    unsigned long long vm0 = __ballot(s_vals[L] > 0.05f);
    unsigned long long vm1 = __ballot((L + 64 < KSEL) ? (s_vals[L + 64] > 0.05f) : false);
    unsigned long long supp0 = 0, supp1 = 0, k0 = 0, k1 = 0;
    for (int j = 0; j < KSEL; ++j) {
      unsigned long long rl, rh;
      bool pass;
      if (j < 64) {
        rl = __shfl(r0, j); rh = __shfl(r1, j);
        pass = ((vm0 >> j) & 1ull) && !((supp0 >> j) & 1ull);
      } else {
        rl = __shfl(r2, j - 64); rh = __shfl(r3, j - 64);
        pass = ((vm1 >> (j - 64)) & 1ull) && !((supp1 >> (j - 64)) & 1ull);
      }
      if (pass) {
        supp0 |= rl; supp1 |= rh;
        if (j < 64) k0 |= 1ull << j; else k1 |= 1ull << (j - 64);
      }
    }
    if (tid == 0) { s_keepw[0] = k0; s_keepw[1] = k1; }
  }
  __syncthreads();

  if (tid < KSEL) {
    bool kept = (tid < 64) ? ((s_keepw[0] >> tid) & 1ull)
                           : ((s_keepw[1] >> (tid - 64)) & 1ull);
    size_t base = (size_t)bc * KSEL + tid;
    candScore[base] = kept ? s_vals[tid] : 0.0f;
    float* cb = candBox + base * 4;
    cb[0] = s_boxv[tid][0]; cb[1] = s_boxv[tid][1];
    cb[2] = s_boxv[tid][2]; cb[3] = s_boxv[tid][3];
  }
}

// ---------- kernel D: per-image final top-100, zero-skipping striped radix ----------
// candScore is degenerate (~half exact 0.0): all zeros map to one key -> one LDS
// bin -> serialized atomics (137k conflict cycles in round 4). Fix: (1) count
// nonzero first and histogram ONLY nonzero keys; (2) stripe each bin across 8
// LDS words (tid&7) so residual clusters serialize 8x less.
#define FSLOT 36   // 36*256 = 9216 >= 9000
__global__ __launch_bounds__(256) void final_topk_kernel(
    const float* __restrict__ candScore,  // [B][C*K]
    const float* __restrict__ candBox,    // [B][C*K][4]
    float* __restrict__ out) {            // [B][MAXD][6]
  __shared__ uint32_t hist[2048 * 8];     // 64 KB, bin-major, 8 stripes
  __shared__ uint32_t sc[256];
  __shared__ uint32_t ws4[64];
  __shared__ int s_bsel;
  __shared__ uint32_t s_Sincl, s_Sexcl;
  __shared__ uint32_t red[4];
  __shared__ uint32_t s_total;
  __shared__ uint32_t s_cnt;
  __shared__ unsigned long long ck[128];

  int b = blockIdx.x, tid = threadIdx.x;
  const float* src = candScore + (size_t)b * MFLAT;

  uint32_t key[FSLOT];
#pragma unroll
  for (int q = 0; q < FSLOT; ++q) {
    int idx = q * 256 + tid;
    key[q] = (idx < MFLAT) ? fkey(src[idx]) : 0u;   // pad key 0 < any real key
  }

  // ---- count strictly-positive scores (key > ZKEY) ----
  uint32_t nzc = 0;
#pragma unroll
  for (int q = 0; q < FSLOT; ++q) nzc += (key[q] > ZKEY) ? 1u : 0u;
  uint32_t nz = blockSum256(nzc, red, &s_total);

  uint32_t cutHi = 0, m_above = 0, cut32 = 0;
  int found = 0, tiepath = 0;
  uint32_t V32 = 0, Texact = (uint32_t)(MFLAT - 1);
  uint32_t tie_r = 0;

  if (nz < 100u) {
    // Degenerate: fewer than 100 positive scores -> take all positives plus
    // lowest-index zeros (matches lax.top_k stable tie order).
    tiepath = 1;
    V32 = ZKEY;
    tie_r = 100u - nz;
  } else {
    const int stripe = tid & 7;
    for (int lvl = 0; lvl < 3; ++lvl) {
      const int shiftLo = (lvl == 0) ? 21 : (lvl == 1) ? 10 : 0;
      const uint32_t mask = (lvl == 2) ? 0x3FFu : 0x7FFu;
      const int nbits = (lvl == 2) ? 10 : 11;

      for (int i = tid; i < 4096; i += 256)
        reinterpret_cast<uint4*>(hist)[i] = make_uint4(0u, 0u, 0u, 0u);
      __syncthreads();
#pragma unroll
      for (int q = 0; q < FSLOT; ++q) {
        uint32_t k = key[q];
        bool in = (k > ZKEY) && ((lvl == 0) ? true : ((k >> (shiftLo + nbits)) == cutHi));
        if (in) atomicAdd(&hist[(((k >> shiftLo) & mask) << 3) + stripe], 1u);
      }
      __syncthreads();

      const uint32_t need = 100u - m_above;

      // per-bin totals: thread owns bins [8t, 8t+8), each bin = 8 stripes (2 uint4)
      uint32_t h[8];
#pragma unroll
      for (int i = 0; i < 8; ++i) {
        uint4 a = reinterpret_cast<uint4*>(hist)[(8 * tid + i) * 2];
        uint4 d = reinterpret_cast<uint4*>(hist)[(8 * tid + i) * 2 + 1];
        h[i] = a.x + a.y + a.z + a.w + d.x + d.y + d.z + d.w;
      }
      sc[tid] = h[0] + h[1] + h[2] + h[3] + h[4] + h[5] + h[6] + h[7];
      if (tid == 0) s_bsel = -1;
      __syncthreads();
      if (tid < 64) {   // wave 0: inclusive suffix over groups of 4 sc-chunks
        uint32_t w = sc[4 * tid] + sc[4 * tid + 1] + sc[4 * tid + 2] + sc[4 * tid + 3];
#pragma unroll
        for (int off = 1; off < 64; off <<= 1) {
          uint32_t v = __shfl_down(w, off, 64);
          if (tid + off < 64) w += v;
        }
        ws4[tid] = w;
      }
      __syncthreads();
      {
        int g = tid >> 2;
        uint32_t above = (g < 63) ? ws4[g + 1] : 0u;
        for (int j = (g << 2) + 3; j > tid; --j) above += sc[j];
        uint32_t run = above;
        int best = -1;
        uint32_t bi = 0, be = 0;
#pragma unroll
        for (int p = 7; p >= 0; --p) {
          run += h[p];
          if (best < 0 && run >= need) { best = 8 * tid + p; bi = run; be = run - h[p]; }
        }
        if (best >= 0) atomicMax(&s_bsel, best);
        __syncthreads();
        if (best >= 0 && best == s_bsel) { s_Sincl = bi; s_Sexcl = be; }
      }
      __syncthreads();

      uint32_t bsel = (uint32_t)s_bsel;
      cutHi = (cutHi << nbits) | bsel;
      if (m_above + s_Sincl <= 128u) {    // candidate set fits -> collect & sort
        cut32 = cutHi << shiftLo;
        found = 1;
        break;
      }
      m_above += s_Sexcl;
      __syncthreads();
    }

    if (!found) {
      // >128 identical positive keys at the cut: index-trimmed exact ties
      tiepath = 1;
      V32 = cutHi;
      tie_r = 100u - m_above;
    }
  }

  if (tiepath) {
    uint32_t lo2 = 0, hi2 = (uint32_t)(MFLAT - 1);
    while (lo2 < hi2) {
      uint32_t mid2 = lo2 + ((hi2 - lo2) >> 1);
      uint32_t cnt = 0;
#pragma unroll
      for (int q = 0; q < FSLOT; ++q) {
        uint32_t idx = (uint32_t)(q * 256 + tid);
        cnt += (key[q] == V32 && idx <= mid2) ? 1u : 0u;
      }
      uint32_t tot = blockSum256(cnt, red, &s_total);
      if (tot >= tie_r) hi2 = mid2; else lo2 = mid2 + 1;
    }
    Texact = lo2;
  }

  // collect candidates (100..128), pad, sort
  if (tid == 0) s_cnt = 0;
  __syncthreads();
#pragma unroll
  for (int q = 0; q < FSLOT; ++q) {
    uint32_t k = key[q];
    uint32_t idx = (uint32_t)(q * 256 + tid);
    bool take = tiepath ? (k > V32 || (k == V32 && idx <= Texact))
                        : (k > ZKEY && k >= cut32);
    if (take) {
      uint32_t p = atomicAdd(&s_cnt, 1u);
      if (p < 128u)
        ck[p] = ((unsigned long long)k << 32) | (unsigned long long)(~idx);
    }
  }
  __syncthreads();
  if (tid < 128 && (uint32_t)tid >= s_cnt) ck[tid] = 0ull;
  __syncthreads();

  // bitonic sort 128 descending by (key, ~idx)
  for (int kk = 2; kk <= 128; kk <<= 1) {
    for (int j = kk >> 1; j > 0; j >>= 1) {
      if (tid < 128) {
        int ixj = tid ^ j;
        if (ixj > tid) {
          unsigned long long a = ck[tid], bb = ck[ixj];
          if ((a < bb) == ((tid & kk) == 0)) { ck[tid] = bb; ck[ixj] = a; }
        }
      }
      __syncthreads();
    }
  }

  if (tid < MAXD) {
    unsigned long long keyv = ck[tid];
    int f = (int)(~(uint32_t)(keyv & 0xFFFFFFFFull));   // flat idx = c*K + k
    int c = f / KSEL;
    float sc2 = keyinv((uint32_t)(keyv >> 32));
    const float* cb = candBox + ((size_t)b * MFLAT + f) * 4;
    float* o = out + ((size_t)b * MAXD + tid) * 6;
    o[0] = cb[0]; o[1] = cb[1]; o[2] = cb[2]; o[3] = cb[3];
    o[4] = (float)c; o[5] = sc2;
  }
}

// ---------- host ----------
extern "C" void kernel_launch(void* const* d_in, const int* in_sizes, int n_in,
                              void* d_out, int out_size, void* d_ws, size_t ws_size,
                              hipStream_t stream) {
  const float* enc = (const float*)d_in[0];      // [B,N,4]
  const float* logits = (const float*)d_in[1];   // [B,N,C]
  const float* anchors = (const float*)d_in[2];  // [N,4]
  float* out = (float*)d_out;                    // [B,100,6]
  char* ws = (char*)d_ws;

  size_t off = 0;
  float* candBox = (float*)(ws + off);   off += (size_t)B_ * C_ * KSEL * 4 * sizeof(float); // 2.30 MB
  float* candScore = (float*)(ws + off); off += (size_t)B_ * C_ * KSEL * sizeof(float);     // 0.58 MB
  uint32_t* candPacked = (uint32_t*)(ws + off);
  off += (size_t)B_ * C_ * NPAIR * sizeof(uint32_t);                                        // 0.74 MB
  uint32_t* candCount = (uint32_t*)(ws + off); off += (size_t)B_ * C_ * sizeof(uint32_t);
  off = (off + 255) & ~(size_t)255;
  uint16_t* keys16T = (uint16_t*)(ws + off);
  size_t needT = off + (size_t)B_ * C_ * NN * sizeof(uint16_t);                             // +47.2 MB
  int transposed = (ws_size >= needT) ? 1 : 0;

  if (transposed) {
    transpose_key16_kernel<<<dim3(NN / 128, B_), 256, 0, stream>>>(logits, keys16T);
    select_kernel<1><<<dim3(C_, B_), 512, 0, stream>>>(keys16T, logits, candPacked, candCount);
  } else {
    select_kernel<0><<<dim3(C_, B_), 512, 0, stream>>>(keys16T, logits, candPacked, candCount);
  }

  sort_nms_kernel<<<dim3(C_, B_), 128, 0, stream>>>(candPacked, candCount, logits,
                                                    enc, anchors, candBox, candScore);

  final_topk_kernel<<<B_, 256, 0, stream>>>(candScore, candBox, out);
}

// Round 6
// 134.362 us; speedup vs baseline: 1.0070x; 1.0070x over previous
//
#include <hip/hip_runtime.h>
#include <stdint.h>
#include <math.h>

#define B_ 16
#define NN 16384
#define C_ 90
#define KSEL 100
#define MAXD 100
#define MFLAT (C_ * KSEL)   // 9000
#define NPAIR 128
#define ZKEY 0x80000000u    // fkey(0.0f)

// ---------- helpers ----------

// monotonic float->uint32 key (order-preserving for all non-NaN floats)
__device__ __forceinline__ uint32_t fkey(float f) {
  uint32_t u = __float_as_uint(f);
  return (u & 0x80000000u) ? ~u : (u | 0x80000000u);
}
__device__ __forceinline__ float keyinv(uint32_t k) {
  uint32_t u = (k & 0x80000000u) ? (k & 0x7FFFFFFFu) : ~k;
  return __uint_as_float(u);
}

// block sum over 512 threads (8 waves)
__device__ __forceinline__ uint32_t blockSum512(uint32_t v, uint32_t* red, uint32_t* s_total) {
  int tid = threadIdx.x;
#pragma unroll
  for (int o = 32; o > 0; o >>= 1) v += __shfl_down(v, o, 64);
  if ((tid & 63) == 0) red[tid >> 6] = v;
  __syncthreads();
  if (tid == 0) {
    uint32_t s = 0;
#pragma unroll
    for (int i = 0; i < 8; ++i) s += red[i];
    *s_total = s;
  }
  __syncthreads();
  return *s_total;
}

// ---------- kernel B: transpose [B,N,C] -> [B,C,N] uint16 keys of RAW logits ----------
// k16 = fkey(logit) >> 16 is order-preserving; sigmoid applied later only to winners.
__global__ __launch_bounds__(256) void transpose_key16_kernel(const float* __restrict__ logits,
                                                              uint16_t* __restrict__ keys16T) {
  __shared__ uint32_t tile[128 * 91];   // 128 n-rows x 90 classes (full fkey32), padded
  int b = blockIdx.y;
  int n0 = blockIdx.x * 128;
  const float4* src4 = reinterpret_cast<const float4*>(logits + ((size_t)b * NN + n0) * C_);
  for (int p = threadIdx.x; p < 2880; p += 256) {   // 128*90/4
    float4 v = src4[p];
    int e = p * 4;
    float vv[4] = {v.x, v.y, v.z, v.w};
#pragma unroll
    for (int j = 0; j < 4; ++j) {
      int ee = e + j;
      tile[(ee / C_) * 91 + (ee % C_)] = fkey(vv[j]);
    }
  }
  __syncthreads();
  uint16_t* dstb = keys16T + (size_t)b * C_ * NN + n0;
  for (int q = threadIdx.x; q < C_ * 16; q += 256) {   // 90 classes x 16 uint4 (8 u16 each)
    int c = q >> 4, g = q & 15;
    int nn2 = g * 8;
    uint4 o;
    o.x = (tile[(nn2 + 0) * 91 + c] >> 16) | (tile[(nn2 + 1) * 91 + c] & 0xFFFF0000u);
    o.y = (tile[(nn2 + 2) * 91 + c] >> 16) | (tile[(nn2 + 3) * 91 + c] & 0xFFFF0000u);
    o.z = (tile[(nn2 + 4) * 91 + c] >> 16) | (tile[(nn2 + 5) * 91 + c] & 0xFFFF0000u);
    o.w = (tile[(nn2 + 6) * 91 + c] >> 16) | (tile[(nn2 + 7) * 91 + c] & 0xFFFF0000u);
    reinterpret_cast<uint4*>(dstb + (size_t)c * NN)[g] = o;
  }
}

// ---------- kernel C1: per-(b,c) radix-select top-100 on 16-bit keys ----------
// 512 threads x 32 u16 keys/thread (16 u32 regs). Level 0: 2048 bins (bits 15:5),
// level 1: 32 bins (bits 4:0, redundant all-thread scan). Writes packed (k16<<16|idx).
template <int TR>
__global__ __launch_bounds__(512, 4) void select_kernel(
    const uint16_t* __restrict__ keys16T,  // [B][C][N] (TR=1)
    const float* __restrict__ logits,      // [B][N][C] raw (TR=0 fallback)
    uint32_t* __restrict__ candPacked,     // [B*C][NPAIR]  (k16<<16)|idx
    uint32_t* __restrict__ candCount) {    // [B*C]
  __shared__ uint32_t hist[2048];
  __shared__ uint32_t sc[512];
  __shared__ uint32_t ws8[64];
  __shared__ int s_bsel;
  __shared__ uint32_t s_Sincl, s_Sexcl;
  __shared__ uint32_t red[8];
  __shared__ uint32_t s_total;
  __shared__ uint32_t s_cnt;

  const int c = blockIdx.x, b = blockIdx.y;
  const int tid = threadIdx.x;

  // ---- load 32 u16 keys/thread (16 packed words) ----
  uint32_t keyw[16];
  if (TR) {
    const uint4* src4 = reinterpret_cast<const uint4*>(keys16T + ((size_t)b * C_ + c) * NN);
#pragma unroll
    for (int q = 0; q < 4; ++q) {
      uint4 kv = src4[q * 512 + tid];
      keyw[4 * q + 0] = kv.x; keyw[4 * q + 1] = kv.y;
      keyw[4 * q + 2] = kv.z; keyw[4 * q + 3] = kv.w;
    }
  } else {
    const float* src = logits + (size_t)b * NN * C_ + c;
#pragma unroll
    for (int m = 0; m < 16; ++m) {
      uint32_t i0 = (uint32_t)((((m >> 2) * 512 + tid) * 8) + ((m & 3) * 2));
      uint32_t klo = fkey(src[(size_t)i0 * C_]) >> 16;
      uint32_t khi = fkey(src[(size_t)(i0 + 1) * C_]) >> 16;
      keyw[m] = klo | (khi << 16);
    }
  }

  // ---- level 0: 2048-bin histogram over bits 15:5 ----
  reinterpret_cast<uint4*>(hist)[tid] = make_uint4(0u, 0u, 0u, 0u);   // 2048 words
  __syncthreads();
#pragma unroll
  for (int m = 0; m < 16; ++m) {
    uint32_t w = keyw[m];
    atomicAdd(&hist[(w & 0xFFFFu) >> 5], 1u);
    atomicAdd(&hist[w >> 21], 1u);   // (w>>16)>>5
  }
  __syncthreads();

  uint32_t m_above = 0;
  uint32_t need = 100u;
  uint32_t cut16 = 0;
  int found = 0;
  int tiepath = 0;
  uint32_t V16 = 0, Texact = NN - 1;

  {
    uint32_t h0 = hist[4 * tid], h1 = hist[4 * tid + 1];
    uint32_t h2 = hist[4 * tid + 2], h3 = hist[4 * tid + 3];
    sc[tid] = h0 + h1 + h2 + h3;
    if (tid == 0) s_bsel = -1;
    __syncthreads();
    if (tid < 64) {   // wave 0: inclusive suffix over 8-chunk groups
      uint32_t w = 0;
      int base = tid * 8;
#pragma unroll
      for (int i = 0; i < 8; ++i) w += sc[base + i];
#pragma unroll
      for (int off = 1; off < 64; off <<= 1) {
        uint32_t v = __shfl_down(w, off, 64);
        if (tid + off < 64) w += v;
      }
      ws8[tid] = w;
    }
    __syncthreads();
    {
      int g = tid >> 3;
      uint32_t above = (g < 63) ? ws8[g + 1] : 0u;
      for (int j = (g << 3) + 7; j > tid; --j) above += sc[j];
      uint32_t run = above;
      int best = -1;
      uint32_t bi = 0, be = 0;
      uint32_t hh[4] = {h0, h1, h2, h3};
#pragma unroll
      for (int p = 3; p >= 0; --p) {
        uint32_t h = hh[p];
        run += h;
        if (best < 0 && run >= need) { best = 4 * tid + p; bi = run; be = run - h; }
      }
      if (best >= 0) atomicMax(&s_bsel, best);
      __syncthreads();
      if (best >= 0 && best == s_bsel) { s_Sincl = bi; s_Sexcl = be; }
    }
    __syncthreads();

    uint32_t bsel = (uint32_t)s_bsel;
    uint32_t Sincl = s_Sincl, Sexcl = s_Sexcl;
    if (Sincl <= (uint32_t)NPAIR) {
      cut16 = bsel << 5;
      found = 1;
    } else {
      m_above = Sexcl;
      need = 100u - m_above;
      // ---- level 1: 32 bins (bits 4:0) within prefix bsel ----
      __syncthreads();
      if (tid < 8) reinterpret_cast<uint4*>(hist)[tid] = make_uint4(0u, 0u, 0u, 0u);
      __syncthreads();
#pragma unroll
      for (int m = 0; m < 16; ++m) {
        uint32_t w = keyw[m];
        uint32_t klo = w & 0xFFFFu, khi = w >> 16;
        if ((klo >> 5) == bsel) atomicAdd(&hist[klo & 31u], 1u);
        if ((khi >> 5) == bsel) atomicAdd(&hist[khi & 31u], 1u);
      }
      __syncthreads();
      // redundant all-thread suffix scan over 32 bins (uniform result)
      uint32_t run = 0;
      int b1 = -1;
      uint32_t Si = 0, Se = 0;
      for (int p = 31; p >= 0; --p) {
        uint32_t h = hist[p];
        run += h;
        if (b1 < 0 && run >= need) { b1 = p; Si = run; Se = run - h; }
      }
      uint32_t cutv = (bsel << 5) | (uint32_t)b1;
      if (m_above + Si <= (uint32_t)NPAIR) {
        cut16 = cutv;
        found = 1;
      } else {
        // >128 exact 16-bit ties at the cut (essentially impossible on real data):
        // fall back to index-trimmed tie handling.
        tiepath = 1;
        V16 = cutv;
        m_above += Se;
        uint32_t r = 100u - m_above;
        uint32_t lo2 = 0, hi2 = NN - 1;
        while (lo2 < hi2) {
          uint32_t mid2 = lo2 + ((hi2 - lo2) >> 1);
          uint32_t cnt = 0;
#pragma unroll
          for (int m = 0; m < 16; ++m) {
            uint32_t w = keyw[m];
            uint32_t i0 = (uint32_t)((((m >> 2) * 512 + tid) * 8) + ((m & 3) * 2));
            cnt += ((w & 0xFFFFu) == V16 && i0 <= mid2) ? 1u : 0u;
            cnt += ((w >> 16) == V16 && (i0 + 1) <= mid2) ? 1u : 0u;
          }
          uint32_t tot = blockSum512(cnt, red, &s_total);
          if (tot >= r) hi2 = mid2; else lo2 = mid2 + 1;
        }
        Texact = lo2;
      }
    }
  }

  // ---- collect candidates (100..128) to GLOBAL, unsorted, packed u32 ----
  if (tid == 0) s_cnt = 0;
  __syncthreads();
  uint32_t* outp = candPacked + (size_t)(b * C_ + c) * NPAIR;
#pragma unroll
  for (int m = 0; m < 16; ++m) {
    uint32_t w = keyw[m];
    uint32_t i0 = (uint32_t)((((m >> 2) * 512 + tid) * 8) + ((m & 3) * 2));
    uint32_t klo = w & 0xFFFFu, khi = w >> 16;
    bool t0 = tiepath ? (klo > V16 || (klo == V16 && i0 <= Texact)) : (klo >= cut16);
    bool t1 = tiepath ? (khi > V16 || (khi == V16 && (i0 + 1) <= Texact)) : (khi >= cut16);
    if (t0) {
      uint32_t p = atomicAdd(&s_cnt, 1u);
      if (p < (uint32_t)NPAIR) outp[p] = (klo << 16) | i0;
    }
    if (t1) {
      uint32_t p = atomicAdd(&s_cnt, 1u);
      if (p < (uint32_t)NPAIR) outp[p] = (khi << 16) | (i0 + 1);
    }
  }
  __syncthreads();
  if (tid == 0) candCount[b * C_ + c] = (s_cnt > (uint32_t)NPAIR) ? (uint32_t)NPAIR : s_cnt;
}

// ---------- kernel C2: per-(b,c) exact re-score + sort + decode + bitmask NMS ----------
__global__ __launch_bounds__(128, 4) void sort_nms_kernel(
    const uint32_t* __restrict__ candPacked,  // [B*C][NPAIR]
    const uint32_t* __restrict__ candCount,   // [B*C]
    const float* __restrict__ logits,         // [B][N][C]
    const float* __restrict__ enc,            // [B][N][4]
    const float* __restrict__ anchors,        // [N][4]
    float* __restrict__ candBox,              // [B][C][K][4]
    float* __restrict__ candScore) {          // [B][C][K]
  __shared__ unsigned long long ck[NPAIR];
  __shared__ float s_vals[KSEL];
  __shared__ float s_boxv[KSEL][5];   // padded to 5 to spread LDS banks
  __shared__ float s_area[KSEL];
  __shared__ uint32_t smask[KSEL][4]; // row i: bitmask of victims j (j>i, iou>=thr)
  __shared__ unsigned long long s_keepw[2];

  const int c = blockIdx.x, b = blockIdx.y;
  const int tid = threadIdx.x;
  const int bc = b * C_ + c;

  uint32_t cnt = candCount[bc];
  unsigned long long ckv = 0ull;
  if (tid < (int)cnt) {
    uint32_t v = candPacked[(size_t)bc * NPAIR + tid];
    int n = (int)(v & 0x3FFFu);
    float x = logits[((size_t)b * NN + n) * C_ + c];
    float s = 1.0f / (1.0f + expf(-x));
    ckv = ((unsigned long long)fkey(s) << 32) | (unsigned long long)(~(uint32_t)n);
  }
  ck[tid] = ckv;
  __syncthreads();

  // bitonic sort 128 descending by (exact sigmoid key, ~idx)
  for (int kk = 2; kk <= 128; kk <<= 1) {
    for (int j = kk >> 1; j > 0; j >>= 1) {
      int ixj = tid ^ j;
      if (ixj > tid) {
        unsigned long long a = ck[tid], bb2 = ck[ixj];
        if ((a < bb2) == ((tid & kk) == 0)) { ck[tid] = bb2; ck[ixj] = a; }
      }
      __syncthreads();
    }
  }

  // decode rank tid -> (score, box, area)   (cnt >= 100 always)
  if (tid < KSEL) {
    unsigned long long keyv = ck[tid];
    uint32_t hk = (uint32_t)(keyv >> 32);
    int n = (int)(~(uint32_t)(keyv & 0xFFFFFFFFull)) & (NN - 1);
    s_vals[tid] = keyinv(hk);
    float4 e = reinterpret_cast<const float4*>(enc)[(size_t)b * NN + n];
    float4 a = reinterpret_cast<const float4*>(anchors)[n];
    float ha = a.z - a.x, wa = a.w - a.y;
    float cya = (a.x + a.z) * 0.5f, cxa = (a.y + a.w) * 0.5f;
    float cy = (e.x / 10.0f) * ha + cya;
    float cx = (e.y / 10.0f) * wa + cxa;
    float h = expf(e.z / 5.0f) * ha;
    float w = expf(e.w / 5.0f) * wa;
    float y1 = fminf(fmaxf(cy - h * 0.5f, 0.0f), 1.0f);
    float x1 = fminf(fmaxf(cx - w * 0.5f, 0.0f), 1.0f);
    float y2 = fminf(fmaxf(cy + h * 0.5f, 0.0f), 1.0f);
    float x2 = fminf(fmaxf(cx + w * 0.5f, 0.0f), 1.0f);
    s_boxv[tid][0] = y1; s_boxv[tid][1] = x1; s_boxv[tid][2] = y2; s_boxv[tid][3] = x2;
    s_area[tid] = fmaxf(y2 - y1, 0.0f) * fmaxf(x2 - x1, 0.0f);
    smask[tid][0] = 0; smask[tid][1] = 0; smask[tid][2] = 0; smask[tid][3] = 0;
  }
  __syncthreads();

  // parallel IoU matrix over triangular pairs i<j (suppressor i -> victim j)
  for (int p = tid; p < (KSEL * (KSEL - 1)) / 2; p += 128) {
    int j = (int)((1.0f + sqrtf(1.0f + 8.0f * (float)p)) * 0.5f);
    while (j * (j - 1) / 2 > p) --j;
    while ((j + 1) * j / 2 <= p) ++j;
    int i = p - j * (j - 1) / 2;
    float iy1 = s_boxv[i][0], ix1 = s_boxv[i][1], iy2 = s_boxv[i][2], ix2 = s_boxv[i][3];
    float jy1 = s_boxv[j][0], jx1 = s_boxv[j][1], jy2 = s_boxv[j][2], jx2 = s_boxv[j][3];
    float ta = fmaxf(fminf(iy2, jy2) - fmaxf(iy1, jy1), 0.0f) *
               fmaxf(fminf(ix2, jx2) - fmaxf(ix1, jx1), 0.0f);
    float un = fmaxf(s_area[i] + s_area[j] - ta, 1e-8f);
    if (ta / un >= 0.5f) atomicOr(&smask[i][j >> 5], 1u << (j & 31));
  }
  __syncthreads();

  // serial greedy scan, registers + shfl only, on wave 0
  if (tid < 64) {
    int L = tid;
    unsigned long long r0 = (unsigned long long)smask[L][0] |
                            ((unsigned long long)smask[L][1] << 32);
    unsigned long long r1 = (unsigned long long)smask[L][2] |
                            ((unsigned long long)smask[L][3] << 32);
    unsigned long long r2 = 0, r3 = 0;
    if (L < KSEL - 64) {
      r2 = (unsigned long long)smask[L + 64][0] | ((unsigned long long)smask[L + 64][1] << 32);
      r3 = (unsigned long long)smask[L + 64][2] | ((unsigned long long)smask[L + 64][3] << 32);
    }
    unsigned long long vm0 = __ballot(s_vals[L] > 0.05f);
    unsigned long long vm1 = __ballot((L + 64 < KSEL) ? (s_vals[L + 64] > 0.05f) : false);
    unsigned long long supp0 = 0, supp1 = 0, k0 = 0, k1 = 0;
    for (int j = 0; j < KSEL; ++j) {
      unsigned long long rl, rh;
      bool pass;
      if (j < 64) {
        rl = __shfl(r0, j); rh = __shfl(r1, j);
        pass = ((vm0 >> j) & 1ull) && !((supp0 >> j) & 1ull);
      } else {
        rl = __shfl(r2, j - 64); rh = __shfl(r3, j - 64);
        pass = ((vm1 >> (j - 64)) & 1ull) && !((supp1 >> (j - 64)) & 1ull);
      }
      if (pass) {
        supp0 |= rl; supp1 |= rh;
        if (j < 64) k0 |= 1ull << j; else k1 |= 1ull << (j - 64);
      }
    }
    if (tid == 0) { s_keepw[0] = k0; s_keepw[1] = k1; }
  }
  __syncthreads();

  if (tid < KSEL) {
    bool kept = (tid < 64) ? ((s_keepw[0] >> tid) & 1ull)
                           : ((s_keepw[1] >> (tid - 64)) & 1ull);
    size_t base = (size_t)bc * KSEL + tid;
    candScore[base] = kept ? s_vals[tid] : 0.0f;
    float* cb = candBox + base * 4;
    cb[0] = s_boxv[tid][0]; cb[1] = s_boxv[tid][1];
    cb[2] = s_boxv[tid][2]; cb[3] = s_boxv[tid][3];
  }
}

// ---------- kernel D: per-image final top-100, LDS-resident keys ----------
// Rounds 0-5 all spent ~55-65us here regardless of algorithm: the per-thread
// key[36] array spilled to scratch (VGPR_Count 48-100 < live set), and with 16
// blocks x 1 wave/SIMD there is zero TLP to hide the scratch latency. Fix:
// keys live in LDS (36 KB), 512 threads (2 waves/SIMD), wave-private histograms.
#define FT_NT 512
#define FT_SLOTS 18   // 512*18 = 9216 >= 9000
#define FT_NW 8       // 8 waves, wave-private histogram copies
__global__ __launch_bounds__(FT_NT) void final_topk_kernel(
    const float* __restrict__ candScore,  // [B][C*K]
    const float* __restrict__ candBox,    // [B][C*K][4]
    float* __restrict__ out) {            // [B][MAXD][6]
  __shared__ uint32_t skey[FT_NT * FT_SLOTS];   // 36,864 B: all 9216 keys
  __shared__ uint32_t hist[FT_NW * 2048];       // 65,536 B: per-wave histograms
  __shared__ uint32_t sc[512];
  __shared__ uint32_t ws8[64];
  __shared__ int s_bsel;
  __shared__ uint32_t s_Sincl, s_Sexcl;
  __shared__ uint32_t red[8];
  __shared__ uint32_t s_total;
  __shared__ uint32_t s_cnt;
  __shared__ unsigned long long ck[128];

  int b = blockIdx.x, tid = threadIdx.x;
  const int wid = tid >> 6;
  const float* src = candScore + (size_t)b * MFLAT;

  // ---- load keys into LDS (coalesced), count strictly-positive scores ----
  uint32_t nzc = 0;
  for (int q = 0; q < FT_SLOTS; ++q) {
    int idx = q * FT_NT + tid;
    uint32_t k = (idx < MFLAT) ? fkey(src[idx]) : 0u;   // pad key 0 < any real key
    skey[idx] = k;
    nzc += (k > ZKEY) ? 1u : 0u;
  }
  __syncthreads();
  uint32_t nz = blockSum512(nzc, red, &s_total);

  uint32_t cutHi = 0, m_above = 0, cut32 = 0;
  int found = 0, tiepath = 0;
  uint32_t V32 = 0, Texact = (uint32_t)(MFLAT - 1);
  uint32_t tie_r = 0;

  if (nz < 100u) {
    // Degenerate: fewer than 100 positive scores -> take all positives plus
    // lowest-index zeros (matches lax.top_k stable tie order).
    tiepath = 1;
    V32 = ZKEY;
    tie_r = 100u - nz;
  } else {
    for (int lvl = 0; lvl < 3; ++lvl) {
      const int shiftLo = (lvl == 0) ? 21 : (lvl == 1) ? 10 : 0;
      const uint32_t mask = (lvl == 2) ? 0x3FFu : 0x7FFu;
      const int nbits = (lvl == 2) ? 10 : 11;

      for (int i = tid; i < FT_NW * 512; i += FT_NT)   // 16384 words as uint4
        reinterpret_cast<uint4*>(hist)[i] = make_uint4(0u, 0u, 0u, 0u);
      __syncthreads();
      uint32_t* myh = hist + wid * 2048;
      for (int q = 0; q < FT_SLOTS; ++q) {
        uint32_t k = skey[q * FT_NT + tid];
        bool in = (k > ZKEY) && ((lvl == 0) ? true : ((k >> (shiftLo + nbits)) == cutHi));
        if (in) atomicAdd(&myh[(k >> shiftLo) & mask], 1u);
      }
      __syncthreads();

      const uint32_t need = 100u - m_above;

      // per-bin totals (sum 8 wave copies): thread owns bins [4t, 4t+4)
      uint32_t h0 = 0, h1 = 0, h2 = 0, h3 = 0;
#pragma unroll
      for (int w = 0; w < FT_NW; ++w) {
        uint4 a = *reinterpret_cast<const uint4*>(hist + w * 2048 + 4 * tid);
        h0 += a.x; h1 += a.y; h2 += a.z; h3 += a.w;
      }
      sc[tid] = h0 + h1 + h2 + h3;
      if (tid == 0) s_bsel = -1;
      __syncthreads();
      if (tid < 64) {   // wave 0: inclusive suffix over 8-chunk groups
        uint32_t w = 0;
        int base = tid * 8;
#pragma unroll
        for (int i = 0; i < 8; ++i) w += sc[base + i];
#pragma unroll
        for (int off = 1; off < 64; off <<= 1) {
          uint32_t v = __shfl_down(w, off, 64);
          if (tid + off < 64) w += v;
        }
        ws8[tid] = w;
      }
      __syncthreads();
      {
        int g = tid >> 3;
        uint32_t above = (g < 63) ? ws8[g + 1] : 0u;
        for (int j = (g << 3) + 7; j > tid; --j) above += sc[j];
        uint32_t run = above;
        int best = -1;
        uint32_t bi = 0, be = 0;
        uint32_t hh[4] = {h0, h1, h2, h3};
#pragma unroll
        for (int p = 3; p >= 0; --p) {
          uint32_t h = hh[p];
          run += h;
          if (best < 0 && run >= need) { best = 4 * tid + p; bi = run; be = run - h; }
        }
        if (best >= 0) atomicMax(&s_bsel, best);
        __syncthreads();
        if (best >= 0 && best == s_bsel) { s_Sincl = bi; s_Sexcl = be; }
      }
      __syncthreads();

      uint32_t bsel = (uint32_t)s_bsel;
      cutHi = (cutHi << nbits) | bsel;
      if (m_above + s_Sincl <= 128u) {    // candidate set fits -> collect & sort
        cut32 = cutHi << shiftLo;
        found = 1;
        break;
      }
      m_above += s_Sexcl;
      __syncthreads();
    }

    if (!found) {
      // >128 identical positive keys at the cut: index-trimmed exact ties
      tiepath = 1;
      V32 = cutHi;
      tie_r = 100u - m_above;
    }
  }

  if (tiepath) {
    uint32_t lo2 = 0, hi2 = (uint32_t)(MFLAT - 1);
    while (lo2 < hi2) {
      uint32_t mid2 = lo2 + ((hi2 - lo2) >> 1);
      uint32_t cnt = 0;
      for (int q = 0; q < FT_SLOTS; ++q) {
        uint32_t idx = (uint32_t)(q * FT_NT + tid);
        cnt += (skey[idx] == V32 && idx <= mid2) ? 1u : 0u;
      }
      uint32_t tot = blockSum512(cnt, red, &s_total);
      if (tot >= tie_r) hi2 = mid2; else lo2 = mid2 + 1;
    }
    Texact = lo2;
  }

  // collect candidates (100..128), pad, sort
  if (tid == 0) s_cnt = 0;
  __syncthreads();
  for (int q = 0; q < FT_SLOTS; ++q) {
    uint32_t idx = (uint32_t)(q * FT_NT + tid);
    uint32_t k = skey[idx];
    bool take = tiepath ? (k > V32 || (k == V32 && idx <= Texact))
                        : (k > ZKEY && k >= cut32);
    if (take) {
      uint32_t p = atomicAdd(&s_cnt, 1u);
      if (p < 128u)
        ck[p] = ((unsigned long long)k << 32) | (unsigned long long)(~idx);
    }
  }
  __syncthreads();
  if (tid < 128 && (uint32_t)tid >= s_cnt) ck[tid] = 0ull;
  __syncthreads();

  // bitonic sort 128 descending by (key, ~idx)
  for (int kk = 2; kk <= 128; kk <<= 1) {
    for (int j = kk >> 1; j > 0; j >>= 1) {
      if (tid < 128) {
        int ixj = tid ^ j;
        if (ixj > tid) {
          unsigned long long a = ck[tid], bb = ck[ixj];
          if ((a < bb) == ((tid & kk) == 0)) { ck[tid] = bb; ck[ixj] = a; }
        }
      }
      __syncthreads();
    }
  }

  if (tid < MAXD) {
    unsigned long long keyv = ck[tid];
    int f = (int)(~(uint32_t)(keyv & 0xFFFFFFFFull));   // flat idx = c*K + k
    int c = f / KSEL;
    float sc2 = keyinv((uint32_t)(keyv >> 32));
    const float* cb = candBox + ((size_t)b * MFLAT + f) * 4;
    float* o = out + ((size_t)b * MAXD + tid) * 6;
    o[0] = cb[0]; o[1] = cb[1]; o[2] = cb[2]; o[3] = cb[3];
    o[4] = (float)c; o[5] = sc2;
  }
}

// ---------- host ----------
extern "C" void kernel_launch(void* const* d_in, const int* in_sizes, int n_in,
                              void* d_out, int out_size, void* d_ws, size_t ws_size,
                              hipStream_t stream) {
  const float* enc = (const float*)d_in[0];      // [B,N,4]
  const float* logits = (const float*)d_in[1];   // [B,N,C]
  const float* anchors = (const float*)d_in[2];  // [N,4]
  float* out = (float*)d_out;                    // [B,100,6]
  char* ws = (char*)d_ws;

  size_t off = 0;
  float* candBox = (float*)(ws + off);   off += (size_t)B_ * C_ * KSEL * 4 * sizeof(float); // 2.30 MB
  float* candScore = (float*)(ws + off); off += (size_t)B_ * C_ * KSEL * sizeof(float);     // 0.58 MB
  uint32_t* candPacked = (uint32_t*)(ws + off);
  off += (size_t)B_ * C_ * NPAIR * sizeof(uint32_t);                                        // 0.74 MB
  uint32_t* candCount = (uint32_t*)(ws + off); off += (size_t)B_ * C_ * sizeof(uint32_t);
  off = (off + 255) & ~(size_t)255;
  uint16_t* keys16T = (uint16_t*)(ws + off);
  size_t needT = off + (size_t)B_ * C_ * NN * sizeof(uint16_t);                             // +47.2 MB
  int transposed = (ws_size >= needT) ? 1 : 0;

  if (transposed) {
    transpose_key16_kernel<<<dim3(NN / 128, B_), 256, 0, stream>>>(logits, keys16T);
    select_kernel<1><<<dim3(C_, B_), 512, 0, stream>>>(keys16T, logits, candPacked, candCount);
  } else {
    select_kernel<0><<<dim3(C_, B_), 512, 0, stream>>>(keys16T, logits, candPacked, candCount);
  }

  sort_nms_kernel<<<dim3(C_, B_), 128, 0, stream>>>(candPacked, candCount, logits,
                                                    enc, anchors, candBox, candScore);

  final_topk_kernel<<<B_, FT_NT, 0, stream>>>(candScore, candBox, out);
}